// Round 12
// baseline (856.715 us; speedup 1.0000x reference)
//
#include <hip/hip_runtime.h>

typedef unsigned short u16;
typedef unsigned int   u32;
typedef unsigned long long u64;
typedef __attribute__((ext_vector_type(8))) _Float16 f16x8;
typedef __attribute__((ext_vector_type(4))) float f32x4;

#define NPOS (512*512)            // 262144 positions
#define NELEM ((size_t)NPOS*128)  // elements per [pos][c] tensor

__device__ __forceinline__ float b2f(u32 u){ return __uint_as_float(u<<16); }
__device__ __forceinline__ u16 f2b(float f){
  u32 x = __float_as_uint(f);
  return (u16)((x + 0x7fffu + ((x>>16)&1u)) >> 16);
}
// fp16 converts: v_cvt_f16_f32 / v_cvt_f32_f16, RNE, 1 VALU op each
__device__ __forceinline__ u16 f2h(float f){
  _Float16 h = (_Float16)f;
  return __builtin_bit_cast(u16, h);
}
__device__ __forceinline__ float h2f(u16 u){
  return (float)__builtin_bit_cast(_Float16, u);
}
__device__ __forceinline__ float sig(float x){ return 1.f/(1.f+__expf(-x)); }
// dtype-agnostic scalar load: f32flag ? fp32 : bf16
__device__ __forceinline__ float ldf(const void* p, size_t i, int f32){
  return f32 ? ((const float*)p)[i] : b2f(((const u16*)p)[i]);
}

// ---------------------------------------------------------------------------
// kdetect: decide whether tensors are fp32 or bf16 by decoding the first 64
// words of x2d as packed bf16 pairs. fp32 data -> low halves are random
// mantissa bits -> many decode with exponent>=134 (|v|>=128 or NaN/Inf).
// Genuine bf16 N(0,1) data -> none do.
// ---------------------------------------------------------------------------
__global__ void kdetect(const u32* __restrict__ x, u32* __restrict__ flag){
  u32 w = x[threadIdx.x];
  u32 e0 = (w>>7)&0xffu, e1 = (w>>23)&0xffu;
  int bad = (e0 >= 134u || e1 >= 134u) ? 1 : 0;
  u64 m = __ballot(bad);
  if (threadIdx.x==0) *flag = (__popcll(m) >= 4) ? 1u : 0u;
}

// ---------------------------------------------------------------------------
// K0: transpose the 6 weight matrices [k][n] -> fp16 [n][k] into WT.
// Planes: 0:Wi 1:Wis 2:Wj 3:Wjs 4:Ws 5:Wp
// ---------------------------------------------------------------------------
__global__ void k0_transpose(const void* __restrict__ Wi, const void* __restrict__ Wis,
                             const void* __restrict__ Wj, const void* __restrict__ Wjs,
                             const void* __restrict__ Ws, const void* __restrict__ Wp,
                             u16* __restrict__ WT, const u32* __restrict__ flag)
{
  const int f32 = (int)*flag;
  const void* srcs[6] = {Wi, Wis, Wj, Wjs, Ws, Wp};
  const void* W = srcs[blockIdx.x];
  u16* dst = WT + (size_t)blockIdx.x*16384;
  for (int f = threadIdx.x; f < 16384; f += 256){
    int k = f >> 7, n = f & 127;
    dst[n*128 + k] = f2h(ldf(W, f, f32));
  }
}

// ---------------------------------------------------------------------------
// K2: fused LN + 5-way projection. Per workgroup: 64 positions.
// Redesigned vs 283us version (same recipe that fixed K4):
//  - NO ldsW, NO stageW: B-fragments for all 5 weight matrices read DIRECTLY
//    from the L2-resident WT planes (identical addresses across all 4096
//    blocks). Removes 5 stage phases, all 10 barriers, and the 8-way
//    bank-conflicted ldsW writes/reads (16.7M conflict cycles/dispatch).
//  - LDS 52KB -> 17KB: occupancy cap 3 -> ~6 blocks/CU (VGPR-limited).
//  - ZERO __syncthreads: the X-stage rows (t>>2) for wave w are exactly rows
//    w*16..w*16+15 -- the same rows wave w's LN pass and afr reads touch.
//    All LDS dataflow is wave-local.
// LN(x) in LDS (fp16), then i=(xWi+bi)*sig(xWis+bis)*mask -> iT [c][pos];
// j likewise -> jT; gate=sig(xWs+bs) -> d_out [pos][c] (output dtype).
// ---------------------------------------------------------------------------
__global__ __launch_bounds__(256) void k2_proj(
    const void* __restrict__ x, const u16* __restrict__ WT,
    const void* __restrict__ g1, const void* __restrict__ b1,
    const void* __restrict__ mask,
    const void* __restrict__ bi, const void* __restrict__ bis,
    const void* __restrict__ bj, const void* __restrict__ bjs,
    const void* __restrict__ bsv,
    u16* __restrict__ iT, u16* __restrict__ jT, void* __restrict__ gate,
    const u32* __restrict__ flag)
{
  __shared__ u16 ldsX[64*136];
  const int f32 = (int)*flag;
  const int t = threadIdx.x;
  const int R = blockIdx.x*64;

  { // stage X tile as fp16 (convert from fp32 or bf16); rows are wave-local
    int row = t>>2, seg = t&3;
    u16* d = ldsX + row*136 + seg*32;
    if (f32){
      const float* s = (const float*)x + (size_t)(R+row)*128 + seg*32;
      #pragma unroll
      for (int e=0;e<32;e+=4){
        float4 v = *(const float4*)(s+e);
        d[e]=f2h(v.x); d[e+1]=f2h(v.y); d[e+2]=f2h(v.z); d[e+3]=f2h(v.w);
      }
    } else {
      const uint4* sv = (const uint4*)((const u16*)x + (size_t)(R+row)*128 + seg*32);
      #pragma unroll
      for (int q2=0;q2<4;q2++){
        uint4 pk = sv[q2];
        u32 wv[4] = {pk.x, pk.y, pk.z, pk.w};
        #pragma unroll
        for (int h=0;h<4;h++){
          d[q2*8+h*2]   = f2h(b2f(wv[h]&0xffffu));
          d[q2*8+h*2+1] = f2h(b2f(wv[h]>>16));
        }
      }
    }
  }
  // no barrier: wave w staged exactly rows w*16..w*16+15 (t>>2 mapping)

  const int lane = t&63, w = t>>6, quad = lane>>4, l16 = lane&15;

  { // LayerNorm rows w*16..w*16+15 in LDS (each wave owns its rows)
    float gv0 = ldf(g1, lane*2,   f32), gv1 = ldf(g1, lane*2+1, f32);
    float bv0 = ldf(b1, lane*2,   f32), bv1 = ldf(b1, lane*2+1, f32);
    for (int rr=0;rr<16;rr++){
      int row = w*16+rr;
      u32 u = *(const u32*)(ldsX + row*136 + lane*2);
      float v0=h2f((u16)(u&0xffffu)), v1=h2f((u16)(u>>16));
      float s=v0+v1, q=v0*v0+v1*v1;
      #pragma unroll
      for (int off=32;off;off>>=1){ s+=__shfl_xor(s,off,64); q+=__shfl_xor(q,off,64); }
      float mu=s*(1.f/128.f), var=q*(1.f/128.f)-mu*mu, rs=rsqrtf(var+1e-5f);
      float y0=(v0-mu)*rs*gv0+bv0, y1=(v1-mu)*rs*gv1+bv1;
      *(u32*)(ldsX + row*136 + lane*2) = (u32)f2h(y0) | ((u32)f2h(y1)<<16);
    }
  }

  const int m0 = w*16;
  f16x8 afr[4];
  #pragma unroll
  for (int s=0;s<4;s++)
    afr[s] = *(const f16x8*)(ldsX + (m0+l16)*136 + s*32 + quad*8);

  float maskv[4];
  #pragma unroll
  for (int r=0;r<4;r++) maskv[r] = ldf(mask, (size_t)(R + m0 + quad*4 + r), f32);

  f32x4 accA[8], accB[8];

  // B-fragments straight from global WT plane (L2-resident, block-uniform)
  auto compute = [&](const u16* Wg, f32x4* acc){
    #pragma unroll
    for (int ct=0;ct<8;ct++){
      f32x4 a = {0.f,0.f,0.f,0.f};
      const u16* wr = Wg + (ct*16 + l16)*128 + quad*8;
      #pragma unroll
      for (int s=0;s<4;s++){
        f16x8 bfr = *(const f16x8*)(wr + s*32);
        a = __builtin_amdgcn_mfma_f32_16x16x32_f16(afr[s], bfr, a, 0,0,0);
      }
      acc[ct]=a;
    }
  };

  // ---- i = (xWi+bi)*sig(xWis+bis)*mask -> iT [c][pos] ----
  compute(WT + (size_t)0*16384, accA);
  compute(WT + (size_t)1*16384, accB);
  #pragma unroll
  for (int ct=0;ct<8;ct++){
    int c = ct*16 + l16;
    float ba = ldf(bi, c, f32), bb = ldf(bis, c, f32);
    #pragma unroll
    for (int r=0;r<4;r++){
      size_t pos = (size_t)(R + m0 + quad*4 + r);
      float v = (accA[ct][r]+ba) * sig(accB[ct][r]+bb) * maskv[r];
      iT[(size_t)c*NPOS + pos] = f2h(v);
    }
  }
  // ---- j = (xWj+bj)*sig(xWjs+bjs)*mask -> jT [c][pos] ----
  compute(WT + (size_t)2*16384, accA);
  compute(WT + (size_t)3*16384, accB);
  #pragma unroll
  for (int ct=0;ct<8;ct++){
    int c = ct*16 + l16;
    float ba = ldf(bj, c, f32), bb = ldf(bjs, c, f32);
    #pragma unroll
    for (int r=0;r<4;r++){
      size_t pos = (size_t)(R + m0 + quad*4 + r);
      float v = (accA[ct][r]+ba) * sig(accB[ct][r]+bb) * maskv[r];
      jT[(size_t)c*NPOS + pos] = f2h(v);
    }
  }
  // ---- gate = sig(xWs+bs) -> d_out [pos][c], output dtype ----
  compute(WT + (size_t)4*16384, accA);
  #pragma unroll
  for (int ct=0;ct<8;ct++){
    int c = ct*16 + l16;
    float bg = ldf(bsv, c, f32);
    #pragma unroll
    for (int r=0;r<4;r++){
      size_t pos = (size_t)(R + m0 + quad*4 + r);
      float v = sig(accA[ct][r]+bg);
      if (f32) ((float*)gate)[pos*128 + c] = v;
      else     ((u16*) gate)[pos*128 + c] = f2b(v);
    }
  }
}

// ---------------------------------------------------------------------------
// K3: per-channel einsum. outp[c][i][j] = sum_k iT[c][i][k]*jT[c][j][k]
// 128 independent 512x512x512 NT-GEMMs. 64x64 C-tile per workgroup. All fp16.
// ---------------------------------------------------------------------------
__global__ __launch_bounds__(256) void k3_einsum(const u16* __restrict__ iT,
                                                 const u16* __restrict__ jT,
                                                 u16* __restrict__ outp)
{
  __shared__ u16 ldsA[64*72];
  __shared__ u16 ldsB[64*72];
  const int t = threadIdx.x;
  const int tj = blockIdx.x, ti = blockIdx.y, c = blockIdx.z;
  const u16* A = iT + (size_t)c*NPOS;
  const u16* B = jT + (size_t)c*NPOS;
  const int lane=t&63, w=t>>6, quad=lane>>4, l16=lane&15;
  const int mrow0 = (w>>1)*32, ncol0 = (w&1)*32;
  f32x4 acc00={0,0,0,0}, acc01={0,0,0,0}, acc10={0,0,0,0}, acc11={0,0,0,0};
  const int arow = t>>2, aseg = t&3;

  for (int k0=0;k0<512;k0+=64){
    { const uint4* s=(const uint4*)(A + (size_t)(ti*64+arow)*512 + k0 + aseg*16);
      uint4* d=(uint4*)(ldsA + arow*72 + aseg*16); d[0]=s[0]; d[1]=s[1]; }
    { const uint4* s=(const uint4*)(B + (size_t)(tj*64+arow)*512 + k0 + aseg*16);
      uint4* d=(uint4*)(ldsB + arow*72 + aseg*16); d[0]=s[0]; d[1]=s[1]; }
    __syncthreads();
    #pragma unroll
    for (int s=0;s<2;s++){
      int ko = s*32 + quad*8;
      f16x8 a0 = *(const f16x8*)(ldsA + (mrow0+   l16)*72 + ko);
      f16x8 a1 = *(const f16x8*)(ldsA + (mrow0+16+l16)*72 + ko);
      f16x8 b0 = *(const f16x8*)(ldsB + (ncol0+   l16)*72 + ko);
      f16x8 b1 = *(const f16x8*)(ldsB + (ncol0+16+l16)*72 + ko);
      acc00 = __builtin_amdgcn_mfma_f32_16x16x32_f16(a0,b0,acc00,0,0,0);
      acc01 = __builtin_amdgcn_mfma_f32_16x16x32_f16(a0,b1,acc01,0,0,0);
      acc10 = __builtin_amdgcn_mfma_f32_16x16x32_f16(a1,b0,acc10,0,0,0);
      acc11 = __builtin_amdgcn_mfma_f32_16x16x32_f16(a1,b1,acc11,0,0,0);
    }
    __syncthreads();
  }
  u16* O = outp + (size_t)c*NPOS;
  #pragma unroll
  for (int mi=0;mi<2;mi++){
    #pragma unroll
    for (int ni=0;ni<2;ni++){
      f32x4 a = mi==0 ? (ni==0?acc00:acc01) : (ni==0?acc10:acc11);
      #pragma unroll
      for (int r=0;r<4;r++){
        int row = ti*64 + mrow0 + mi*16 + quad*4 + r;
        int col = tj*64 + ncol0 + ni*16 + l16;
        O[(size_t)row*512 + col] = f2h(a[r]);
      }
    }
  }
}

// ---------------------------------------------------------------------------
// K4: LN(outp) @ Wp + bp, * gate * mask -> final output [pos][c].
//  - Wp pre-transposed by K0 (plane 5) -> B-frags read DIRECTLY from global
//    (L2-resident, same addrs for all blocks). No ldsW. LDS 17KB.
//  - Epilogue: acc(+bp) -> fp16 in ldsX [pos][c], barrier, then coalesced
//    uint4/float4 gate-RMW (wave = 16 consecutive positions x 256B).
// gate lives in d_out: read-modify-write of the same addresses (vectorized,
// same thread reads gate before overwriting).
// ---------------------------------------------------------------------------
__global__ __launch_bounds__(256) void k4_final(
    const u16* __restrict__ outp, const u16* __restrict__ WTp,
    const void* __restrict__ g2, const void* __restrict__ b2v,
    const void* __restrict__ bp,
    const void* __restrict__ mask, void* __restrict__ out,
    const u32* __restrict__ flag)
{
  __shared__ u16 ldsX[64*136];
  const int f32 = (int)*flag;
  const int t = threadIdx.x;
  const int P = blockIdx.x*64;

  { // gather 64 positions x 128 channels from channel-major outp; transpose in LDS
    int cc = t>>1, half = t&1;
    const uint4* sv = (const uint4*)(outp + (size_t)cc*NPOS + P + half*32);
    union { uint4 v[4]; u16 u[32]; } buf;
    buf.v[0]=sv[0]; buf.v[1]=sv[1]; buf.v[2]=sv[2]; buf.v[3]=sv[3];
    #pragma unroll
    for (int e=0;e<32;e++) ldsX[(half*32+e)*136 + cc] = buf.u[e];
  }
  __syncthreads();

  const int lane=t&63, w=t>>6, quad=lane>>4, l16=lane&15;

  { // LN over channels: wave w owns rows w*16 .. w*16+15
    float gv0 = ldf(g2, lane*2,   f32), gv1 = ldf(g2, lane*2+1, f32);
    float bv0 = ldf(b2v, lane*2,  f32), bv1 = ldf(b2v, lane*2+1, f32);
    for (int rr=0;rr<16;rr++){
      int row = w*16+rr;
      u32 u = *(const u32*)(ldsX + row*136 + lane*2);
      float v0=h2f((u16)(u&0xffffu)), v1=h2f((u16)(u>>16));
      float s=v0+v1, q=v0*v0+v1*v1;
      #pragma unroll
      for (int off=32;off;off>>=1){ s+=__shfl_xor(s,off,64); q+=__shfl_xor(q,off,64); }
      float mu = s*(1.f/128.f), var = q*(1.f/128.f)-mu*mu, rs = rsqrtf(var+1e-5f);
      float y0=(v0-mu)*rs*gv0+bv0, y1=(v1-mu)*rs*gv1+bv1;
      *(u32*)(ldsX + row*136 + lane*2) = (u32)f2h(y0) | ((u32)f2h(y1)<<16);
    }
  }
  // each wave reads back only its own LN'd rows -> no barrier needed

  const int m0 = w*16;
  f16x8 afr[4];
  #pragma unroll
  for (int s=0;s<4;s++)
    afr[s] = *(const f16x8*)(ldsX + (m0+l16)*136 + s*32 + quad*8);

  f32x4 acc[8];
  #pragma unroll
  for (int ct=0;ct<8;ct++){
    f32x4 a = {0.f,0.f,0.f,0.f};
    const u16* wr = WTp + (ct*16 + l16)*128 + quad*8;   // global, L2-resident
    #pragma unroll
    for (int s=0;s<4;s++){
      f16x8 bfr = *(const f16x8*)(wr + s*32);
      a = __builtin_amdgcn_mfma_f32_16x16x32_f16(afr[s], bfr, a, 0,0,0);
    }
    acc[ct]=a;
  }

  // epilogue stage 1: acc(+bp) -> ldsX [pos][c] fp16 (own-wave rows only;
  // afr already in registers, so overwriting is safe without a barrier)
  #pragma unroll
  for (int ct=0;ct<8;ct++){
    int c = ct*16 + l16;
    float bpv = ldf(bp, c, f32);
    #pragma unroll
    for (int r=0;r<4;r++)
      ldsX[(m0+quad*4+r)*136 + c] = f2h(acc[ct][r]+bpv);
  }
  __syncthreads();

  { // epilogue stage 2: coalesced gate-RMW. thread -> (row, 32-channel seg)
    int row = t>>2, seg = t&3;
    size_t pos = (size_t)(P + row);
    float mv = ldf(mask, pos, f32);
    const u16* src = ldsX + row*136 + seg*32;
    if (f32){
      float* op = (float*)out + pos*128 + seg*32;
      #pragma unroll
      for (int i=0;i<8;i++){
        float4 g = *(const float4*)(op + i*4);
        float4 o;
        o.x = h2f(src[i*4+0])*g.x*mv;
        o.y = h2f(src[i*4+1])*g.y*mv;
        o.z = h2f(src[i*4+2])*g.z*mv;
        o.w = h2f(src[i*4+3])*g.w*mv;
        *(float4*)(op + i*4) = o;
      }
    } else {
      u16* op = (u16*)out + pos*128 + seg*32;
      #pragma unroll
      for (int i=0;i<4;i++){
        uint4 g = *(const uint4*)(op + i*8);
        u32 gw[4] = {g.x, g.y, g.z, g.w};
        u32 ow[4];
        #pragma unroll
        for (int h=0;h<4;h++){
          float g0 = b2f(gw[h]&0xffffu), g1 = b2f(gw[h]>>16);
          float y0 = h2f(src[i*8+h*2])  *g0*mv;
          float y1 = h2f(src[i*8+h*2+1])*g1*mv;
          ow[h] = (u32)f2b(y0) | ((u32)f2b(y1)<<16);
        }
        uint4 ov = {ow[0], ow[1], ow[2], ow[3]};
        *(uint4*)(op + i*8) = ov;
      }
    }
  }
}

// ---------------------------------------------------------------------------
extern "C" void kernel_launch(void* const* d_in, const int* in_sizes, int n_in,
                              void* d_out, int out_size, void* d_ws, size_t ws_size,
                              hipStream_t stream)
{
  const void* x2d  = d_in[0];
  const void* mask = d_in[1];
  const void* g1   = d_in[2];
  const void* b1   = d_in[3];
  const void* g2   = d_in[4];
  const void* b2   = d_in[5];
  const void* Wi   = d_in[6];
  const void* bi   = d_in[7];
  const void* Wis  = d_in[8];
  const void* bis  = d_in[9];
  const void* Wj   = d_in[10];
  const void* bj   = d_in[11];
  const void* Wjs  = d_in[12];
  const void* bjs  = d_in[13];
  const void* Wp   = d_in[14];
  const void* bp   = d_in[15];
  const void* Ws   = d_in[16];
  const void* bs   = d_in[17];

  // ws layout: [flag u32][pad][WT 6x16384 fp16 @ +128B][iT|jT|outp @ +2MiB]
  u32* flag = (u32*)d_ws;
  u16* WT   = (u16*)d_ws + 64;
  u16* iT   = (u16*)d_ws + ((size_t)1<<20);   // +2 MiB
  u16* jT   = iT + NELEM;
  u16* outp = jT + NELEM;
  // gate lives in d_out.

  kdetect<<<1, 64, 0, stream>>>((const u32*)x2d, flag);
  k0_transpose<<<6, 256, 0, stream>>>(Wi, Wis, Wj, Wjs, Ws, Wp, WT, flag);
  k2_proj<<<NPOS/64, 256, 0, stream>>>(x2d, WT, g1, b1, mask, bi, bis, bj, bjs, bs,
                                       iT, jT, d_out, flag);
  k3_einsum<<<dim3(8,8,128), 256, 0, stream>>>(iT, jT, outp);
  k4_final<<<NPOS/64, 256, 0, stream>>>(outp, WT + (size_t)5*16384, g2, b2, bp,
                                        mask, d_out, flag);
}

// Round 14
// 633.081 us; speedup vs baseline: 1.3532x; 1.3532x over previous
//
#include <hip/hip_runtime.h>

typedef unsigned short u16;
typedef unsigned int   u32;
typedef unsigned long long u64;
typedef __attribute__((ext_vector_type(8))) _Float16 f16x8;
typedef __attribute__((ext_vector_type(4))) float f32x4;

#define NPOS (512*512)            // 262144 positions
#define NELEM ((size_t)NPOS*128)  // elements per [pos][c] tensor

__device__ __forceinline__ float b2f(u32 u){ return __uint_as_float(u<<16); }
__device__ __forceinline__ u16 f2b(float f){
  u32 x = __float_as_uint(f);
  return (u16)((x + 0x7fffu + ((x>>16)&1u)) >> 16);
}
// fp16 converts: v_cvt_f16_f32 / v_cvt_f32_f16, RNE, 1 VALU op each
__device__ __forceinline__ u16 f2h(float f){
  _Float16 h = (_Float16)f;
  return __builtin_bit_cast(u16, h);
}
__device__ __forceinline__ float h2f(u16 u){
  return (float)__builtin_bit_cast(_Float16, u);
}
__device__ __forceinline__ float sig(float x){ return 1.f/(1.f+__expf(-x)); }
// dtype-agnostic scalar load: f32flag ? fp32 : bf16
__device__ __forceinline__ float ldf(const void* p, size_t i, int f32){
  return f32 ? ((const float*)p)[i] : b2f(((const u16*)p)[i]);
}

// ---------------------------------------------------------------------------
// kdetect: decide whether tensors are fp32 or bf16 by decoding the first 64
// words of x2d as packed bf16 pairs. fp32 data -> low halves are random
// mantissa bits -> many decode with exponent>=134 (|v|>=128 or NaN/Inf).
// Genuine bf16 N(0,1) data -> none do.
// ---------------------------------------------------------------------------
__global__ void kdetect(const u32* __restrict__ x, u32* __restrict__ flag){
  u32 w = x[threadIdx.x];
  u32 e0 = (w>>7)&0xffu, e1 = (w>>23)&0xffu;
  int bad = (e0 >= 134u || e1 >= 134u) ? 1 : 0;
  u64 m = __ballot(bad);
  if (threadIdx.x==0) *flag = (__popcll(m) >= 4) ? 1u : 0u;
}

// ---------------------------------------------------------------------------
// K0: transpose the 6 weight matrices [k][n] -> fp16 [n][k] into WT.
// Planes: 0:Wi 1:Wis 2:Wj 3:Wjs 4:Ws 5:Wp
// ---------------------------------------------------------------------------
__global__ void k0_transpose(const void* __restrict__ Wi, const void* __restrict__ Wis,
                             const void* __restrict__ Wj, const void* __restrict__ Wjs,
                             const void* __restrict__ Ws, const void* __restrict__ Wp,
                             u16* __restrict__ WT, const u32* __restrict__ flag)
{
  const int f32 = (int)*flag;
  const void* srcs[6] = {Wi, Wis, Wj, Wjs, Ws, Wp};
  const void* W = srcs[blockIdx.x];
  u16* dst = WT + (size_t)blockIdx.x*16384;
  for (int f = threadIdx.x; f < 16384; f += 256){
    int k = f >> 7, n = f & 127;
    dst[n*128 + k] = f2h(ldf(W, f, f32));
  }
}

// ---------------------------------------------------------------------------
// K2: fused LN + 5-way projection. Per workgroup: 128 positions, 512 threads.
// Post-mortem R12: global-direct weights REGRESSED (283->433us) -- per-wave
// L2 weight fetch (4x traffic, no reuse) exposed latency on the serialized
// phase chain. Reverting to the measured-good R9 LDS-staged structure and
// attacking the ACTUAL limiter (phase/barrier serialization at 12 waves/CU):
//  - 128 rows x 8 waves per block: barriers/CU and weight-stage traffic HALVE
//    (2048 blocks re-stage 160KB instead of 4096), residency 12 -> 16
//    waves/CU (2 blocks x 8 waves @ 69.6KB LDS).
//  - All wave-locality invariants preserved: X-stage rows (t>>2) == LN rows
//    == afr rows for each wave (rows 16w..16w+15).
// LN(x) in LDS (fp16), then i=(xWi+bi)*sig(xWis+bis)*mask -> iT [c][pos];
// j likewise -> jT; gate=sig(xWs+bs) -> d_out [pos][c] (output dtype).
// ---------------------------------------------------------------------------
__global__ __launch_bounds__(512) void k2_proj(
    const void* __restrict__ x, const u16* __restrict__ WT,
    const void* __restrict__ g1, const void* __restrict__ b1,
    const void* __restrict__ mask,
    const void* __restrict__ bi, const void* __restrict__ bis,
    const void* __restrict__ bj, const void* __restrict__ bjs,
    const void* __restrict__ bsv,
    u16* __restrict__ iT, u16* __restrict__ jT, void* __restrict__ gate,
    const u32* __restrict__ flag)
{
  __shared__ u16 ldsX[128*136];
  __shared__ u16 ldsW[128*136];
  const int f32 = (int)*flag;
  const int t = threadIdx.x;
  const int R = blockIdx.x*128;

  { // stage X tile (128 rows) as fp16; rows are wave-local (t>>2)
    int row = t>>2, seg = t&3;
    u16* d = ldsX + row*136 + seg*32;
    if (f32){
      const float* s = (const float*)x + (size_t)(R+row)*128 + seg*32;
      #pragma unroll
      for (int e=0;e<32;e+=4){
        float4 v = *(const float4*)(s+e);
        d[e]=f2h(v.x); d[e+1]=f2h(v.y); d[e+2]=f2h(v.z); d[e+3]=f2h(v.w);
      }
    } else {
      const uint4* sv = (const uint4*)((const u16*)x + (size_t)(R+row)*128 + seg*32);
      #pragma unroll
      for (int q2=0;q2<4;q2++){
        uint4 pk = sv[q2];
        u32 wv[4] = {pk.x, pk.y, pk.z, pk.w};
        #pragma unroll
        for (int h=0;h<4;h++){
          d[q2*8+h*2]   = f2h(b2f(wv[h]&0xffffu));
          d[q2*8+h*2+1] = f2h(b2f(wv[h]>>16));
        }
      }
    }
  }
  // no barrier: wave w staged exactly rows w*16..w*16+15 (t>>2 mapping)

  const int lane = t&63, w = t>>6, quad = lane>>4, l16 = lane&15;

  { // LayerNorm rows w*16..w*16+15 in LDS (each of 8 waves owns its rows)
    float gv0 = ldf(g1, lane*2,   f32), gv1 = ldf(g1, lane*2+1, f32);
    float bv0 = ldf(b1, lane*2,   f32), bv1 = ldf(b1, lane*2+1, f32);
    for (int rr=0;rr<16;rr++){
      int row = w*16+rr;
      u32 u = *(const u32*)(ldsX + row*136 + lane*2);
      float v0=h2f((u16)(u&0xffffu)), v1=h2f((u16)(u>>16));
      float s=v0+v1, q=v0*v0+v1*v1;
      #pragma unroll
      for (int off=32;off;off>>=1){ s+=__shfl_xor(s,off,64); q+=__shfl_xor(q,off,64); }
      float mu=s*(1.f/128.f), var=q*(1.f/128.f)-mu*mu, rs=rsqrtf(var+1e-5f);
      float y0=(v0-mu)*rs*gv0+bv0, y1=(v1-mu)*rs*gv1+bv1;
      *(u32*)(ldsX + row*136 + lane*2) = (u32)f2h(y0) | ((u32)f2h(y1)<<16);
    }
  }

  const int m0 = w*16;
  f16x8 afr[4];
  #pragma unroll
  for (int s=0;s<4;s++)
    afr[s] = *(const f16x8*)(ldsX + (m0+l16)*136 + s*32 + quad*8);

  float maskv[4];
  #pragma unroll
  for (int r=0;r<4;r++) maskv[r] = ldf(mask, (size_t)(R + m0 + quad*4 + r), f32);

  f32x4 accA[8], accB[8];

  auto stageW = [&](int mm){ // 512 threads x 64B = 32KB matrix
    int row = t>>2, q4 = t&3;
    const uint4* s = (const uint4*)(WT + (size_t)mm*16384 + row*128 + q4*32);
    uint4* d = (uint4*)(ldsW + row*136 + q4*32);
    #pragma unroll
    for (int k=0;k<4;k++) d[k]=s[k];
  };
  auto compute = [&](f32x4* acc){
    #pragma unroll
    for (int ct=0;ct<8;ct++){
      f32x4 a = {0.f,0.f,0.f,0.f};
      const u16* wr = ldsW + (ct*16 + l16)*136 + quad*8;
      #pragma unroll
      for (int s=0;s<4;s++){
        f16x8 bfr = *(const f16x8*)(wr + s*32);
        a = __builtin_amdgcn_mfma_f32_16x16x32_f16(afr[s], bfr, a, 0,0,0);
      }
      acc[ct]=a;
    }
  };

  // ---- i = (xWi+bi)*sig(xWis+bis)*mask -> iT [c][pos] ----
  stageW(0); __syncthreads(); compute(accA); __syncthreads();
  stageW(1); __syncthreads(); compute(accB); __syncthreads();
  #pragma unroll
  for (int ct=0;ct<8;ct++){
    int c = ct*16 + l16;
    float ba = ldf(bi, c, f32), bb = ldf(bis, c, f32);
    #pragma unroll
    for (int r=0;r<4;r++){
      size_t pos = (size_t)(R + m0 + quad*4 + r);
      float v = (accA[ct][r]+ba) * sig(accB[ct][r]+bb) * maskv[r];
      iT[(size_t)c*NPOS + pos] = f2h(v);
    }
  }
  // ---- j = (xWj+bj)*sig(xWjs+bjs)*mask -> jT [c][pos] ----
  stageW(2); __syncthreads(); compute(accA); __syncthreads();
  stageW(3); __syncthreads(); compute(accB); __syncthreads();
  #pragma unroll
  for (int ct=0;ct<8;ct++){
    int c = ct*16 + l16;
    float ba = ldf(bj, c, f32), bb = ldf(bjs, c, f32);
    #pragma unroll
    for (int r=0;r<4;r++){
      size_t pos = (size_t)(R + m0 + quad*4 + r);
      float v = (accA[ct][r]+ba) * sig(accB[ct][r]+bb) * maskv[r];
      jT[(size_t)c*NPOS + pos] = f2h(v);
    }
  }
  // ---- gate = sig(xWs+bs) -> d_out [pos][c], output dtype ----
  stageW(4); __syncthreads(); compute(accA); __syncthreads();
  #pragma unroll
  for (int ct=0;ct<8;ct++){
    int c = ct*16 + l16;
    float bg = ldf(bsv, c, f32);
    #pragma unroll
    for (int r=0;r<4;r++){
      size_t pos = (size_t)(R + m0 + quad*4 + r);
      float v = sig(accA[ct][r]+bg);
      if (f32) ((float*)gate)[pos*128 + c] = v;
      else     ((u16*) gate)[pos*128 + c] = f2b(v);
    }
  }
}

// ---------------------------------------------------------------------------
// K3: per-channel einsum. outp[c][i][j] = sum_k iT[c][i][k]*jT[c][j][k]
// 128 independent 512x512x512 NT-GEMMs. 64x64 C-tile per workgroup. All fp16.
// ---------------------------------------------------------------------------
__global__ __launch_bounds__(256) void k3_einsum(const u16* __restrict__ iT,
                                                 const u16* __restrict__ jT,
                                                 u16* __restrict__ outp)
{
  __shared__ u16 ldsA[64*72];
  __shared__ u16 ldsB[64*72];
  const int t = threadIdx.x;
  const int tj = blockIdx.x, ti = blockIdx.y, c = blockIdx.z;
  const u16* A = iT + (size_t)c*NPOS;
  const u16* B = jT + (size_t)c*NPOS;
  const int lane=t&63, w=t>>6, quad=lane>>4, l16=lane&15;
  const int mrow0 = (w>>1)*32, ncol0 = (w&1)*32;
  f32x4 acc00={0,0,0,0}, acc01={0,0,0,0}, acc10={0,0,0,0}, acc11={0,0,0,0};
  const int arow = t>>2, aseg = t&3;

  for (int k0=0;k0<512;k0+=64){
    { const uint4* s=(const uint4*)(A + (size_t)(ti*64+arow)*512 + k0 + aseg*16);
      uint4* d=(uint4*)(ldsA + arow*72 + aseg*16); d[0]=s[0]; d[1]=s[1]; }
    { const uint4* s=(const uint4*)(B + (size_t)(tj*64+arow)*512 + k0 + aseg*16);
      uint4* d=(uint4*)(ldsB + arow*72 + aseg*16); d[0]=s[0]; d[1]=s[1]; }
    __syncthreads();
    #pragma unroll
    for (int s=0;s<2;s++){
      int ko = s*32 + quad*8;
      f16x8 a0 = *(const f16x8*)(ldsA + (mrow0+   l16)*72 + ko);
      f16x8 a1 = *(const f16x8*)(ldsA + (mrow0+16+l16)*72 + ko);
      f16x8 b0 = *(const f16x8*)(ldsB + (ncol0+   l16)*72 + ko);
      f16x8 b1 = *(const f16x8*)(ldsB + (ncol0+16+l16)*72 + ko);
      acc00 = __builtin_amdgcn_mfma_f32_16x16x32_f16(a0,b0,acc00,0,0,0);
      acc01 = __builtin_amdgcn_mfma_f32_16x16x32_f16(a0,b1,acc01,0,0,0);
      acc10 = __builtin_amdgcn_mfma_f32_16x16x32_f16(a1,b0,acc10,0,0,0);
      acc11 = __builtin_amdgcn_mfma_f32_16x16x32_f16(a1,b1,acc11,0,0,0);
    }
    __syncthreads();
  }
  u16* O = outp + (size_t)c*NPOS;
  #pragma unroll
  for (int mi=0;mi<2;mi++){
    #pragma unroll
    for (int ni=0;ni<2;ni++){
      f32x4 a = mi==0 ? (ni==0?acc00:acc01) : (ni==0?acc10:acc11);
      #pragma unroll
      for (int r=0;r<4;r++){
        int row = ti*64 + mrow0 + mi*16 + quad*4 + r;
        int col = tj*64 + ncol0 + ni*16 + l16;
        O[(size_t)row*512 + col] = f2h(a[r]);
      }
    }
  }
}

// ---------------------------------------------------------------------------
// K4: LN(outp) @ Wp + bp, * gate * mask -> final output [pos][c].
//  - Wp pre-transposed by K0 (plane 5) -> B-frags read DIRECTLY from global
//    (L2-resident, same addrs for all blocks). No ldsW. LDS 17KB.
//  - Epilogue: acc(+bp) -> fp16 in ldsX [pos][c], barrier, then coalesced
//    uint4/float4 gate-RMW (wave = 16 consecutive positions x 256B).
// gate lives in d_out: read-modify-write of the same addresses (vectorized,
// same thread reads gate before overwriting).
// ---------------------------------------------------------------------------
__global__ __launch_bounds__(256) void k4_final(
    const u16* __restrict__ outp, const u16* __restrict__ WTp,
    const void* __restrict__ g2, const void* __restrict__ b2v,
    const void* __restrict__ bp,
    const void* __restrict__ mask, void* __restrict__ out,
    const u32* __restrict__ flag)
{
  __shared__ u16 ldsX[64*136];
  const int f32 = (int)*flag;
  const int t = threadIdx.x;
  const int P = blockIdx.x*64;

  { // gather 64 positions x 128 channels from channel-major outp; transpose in LDS
    int cc = t>>1, half = t&1;
    const uint4* sv = (const uint4*)(outp + (size_t)cc*NPOS + P + half*32);
    union { uint4 v[4]; u16 u[32]; } buf;
    buf.v[0]=sv[0]; buf.v[1]=sv[1]; buf.v[2]=sv[2]; buf.v[3]=sv[3];
    #pragma unroll
    for (int e=0;e<32;e++) ldsX[(half*32+e)*136 + cc] = buf.u[e];
  }
  __syncthreads();

  const int lane=t&63, w=t>>6, quad=lane>>4, l16=lane&15;

  { // LN over channels: wave w owns rows w*16 .. w*16+15
    float gv0 = ldf(g2, lane*2,   f32), gv1 = ldf(g2, lane*2+1, f32);
    float bv0 = ldf(b2v, lane*2,  f32), bv1 = ldf(b2v, lane*2+1, f32);
    for (int rr=0;rr<16;rr++){
      int row = w*16+rr;
      u32 u = *(const u32*)(ldsX + row*136 + lane*2);
      float v0=h2f((u16)(u&0xffffu)), v1=h2f((u16)(u>>16));
      float s=v0+v1, q=v0*v0+v1*v1;
      #pragma unroll
      for (int off=32;off;off>>=1){ s+=__shfl_xor(s,off,64); q+=__shfl_xor(q,off,64); }
      float mu = s*(1.f/128.f), var = q*(1.f/128.f)-mu*mu, rs = rsqrtf(var+1e-5f);
      float y0=(v0-mu)*rs*gv0+bv0, y1=(v1-mu)*rs*gv1+bv1;
      *(u32*)(ldsX + row*136 + lane*2) = (u32)f2h(y0) | ((u32)f2h(y1)<<16);
    }
  }
  // each wave reads back only its own LN'd rows -> no barrier needed

  const int m0 = w*16;
  f16x8 afr[4];
  #pragma unroll
  for (int s=0;s<4;s++)
    afr[s] = *(const f16x8*)(ldsX + (m0+l16)*136 + s*32 + quad*8);

  f32x4 acc[8];
  #pragma unroll
  for (int ct=0;ct<8;ct++){
    f32x4 a = {0.f,0.f,0.f,0.f};
    const u16* wr = WTp + (ct*16 + l16)*128 + quad*8;   // global, L2-resident
    #pragma unroll
    for (int s=0;s<4;s++){
      f16x8 bfr = *(const f16x8*)(wr + s*32);
      a = __builtin_amdgcn_mfma_f32_16x16x32_f16(afr[s], bfr, a, 0,0,0);
    }
    acc[ct]=a;
  }

  // epilogue stage 1: acc(+bp) -> ldsX [pos][c] fp16 (own-wave rows only;
  // afr already in registers, so overwriting is safe without a barrier)
  #pragma unroll
  for (int ct=0;ct<8;ct++){
    int c = ct*16 + l16;
    float bpv = ldf(bp, c, f32);
    #pragma unroll
    for (int r=0;r<4;r++)
      ldsX[(m0+quad*4+r)*136 + c] = f2h(acc[ct][r]+bpv);
  }
  __syncthreads();

  { // epilogue stage 2: coalesced gate-RMW. thread -> (row, 32-channel seg)
    int row = t>>2, seg = t&3;
    size_t pos = (size_t)(P + row);
    float mv = ldf(mask, pos, f32);
    const u16* src = ldsX + row*136 + seg*32;
    if (f32){
      float* op = (float*)out + pos*128 + seg*32;
      #pragma unroll
      for (int i=0;i<8;i++){
        float4 g = *(const float4*)(op + i*4);
        float4 o;
        o.x = h2f(src[i*4+0])*g.x*mv;
        o.y = h2f(src[i*4+1])*g.y*mv;
        o.z = h2f(src[i*4+2])*g.z*mv;
        o.w = h2f(src[i*4+3])*g.w*mv;
        *(float4*)(op + i*4) = o;
      }
    } else {
      u16* op = (u16*)out + pos*128 + seg*32;
      #pragma unroll
      for (int i=0;i<4;i++){
        uint4 g = *(const uint4*)(op + i*8);
        u32 gw[4] = {g.x, g.y, g.z, g.w};
        u32 ow[4];
        #pragma unroll
        for (int h=0;h<4;h++){
          float g0 = b2f(gw[h]&0xffffu), g1 = b2f(gw[h]>>16);
          float y0 = h2f(src[i*8+h*2])  *g0*mv;
          float y1 = h2f(src[i*8+h*2+1])*g1*mv;
          ow[h] = (u32)f2b(y0) | ((u32)f2b(y1)<<16);
        }
        uint4 ov = {ow[0], ow[1], ow[2], ow[3]};
        *(uint4*)(op + i*8) = ov;
      }
    }
  }
}

// ---------------------------------------------------------------------------
extern "C" void kernel_launch(void* const* d_in, const int* in_sizes, int n_in,
                              void* d_out, int out_size, void* d_ws, size_t ws_size,
                              hipStream_t stream)
{
  const void* x2d  = d_in[0];
  const void* mask = d_in[1];
  const void* g1   = d_in[2];
  const void* b1   = d_in[3];
  const void* g2   = d_in[4];
  const void* b2   = d_in[5];
  const void* Wi   = d_in[6];
  const void* bi   = d_in[7];
  const void* Wis  = d_in[8];
  const void* bis  = d_in[9];
  const void* Wj   = d_in[10];
  const void* bj   = d_in[11];
  const void* Wjs  = d_in[12];
  const void* bjs  = d_in[13];
  const void* Wp   = d_in[14];
  const void* bp   = d_in[15];
  const void* Ws   = d_in[16];
  const void* bs   = d_in[17];

  // ws layout: [flag u32][pad][WT 6x16384 fp16 @ +128B][iT|jT|outp @ +2MiB]
  u32* flag = (u32*)d_ws;
  u16* WT   = (u16*)d_ws + 64;
  u16* iT   = (u16*)d_ws + ((size_t)1<<20);   // +2 MiB
  u16* jT   = iT + NELEM;
  u16* outp = jT + NELEM;
  // gate lives in d_out.

  kdetect<<<1, 64, 0, stream>>>((const u32*)x2d, flag);
  k0_transpose<<<6, 256, 0, stream>>>(Wi, Wis, Wj, Wjs, Ws, Wp, WT, flag);
  k2_proj<<<NPOS/128, 512, 0, stream>>>(x2d, WT, g1, b1, mask, bi, bis, bj, bjs, bs,
                                        iT, jT, d_out, flag);
  k3_einsum<<<dim3(8,8,128), 256, 0, stream>>>(iT, jT, outp);
  k4_final<<<NPOS/64, 256, 0, stream>>>(outp, WT + (size_t)5*16384, g2, b2, bp,
                                        mask, d_out, flag);
}